// Round 7
// baseline (2227.641 us; speedup 1.0000x reference)
//
#include <hip/hip_runtime.h>

typedef unsigned int uint;
typedef unsigned short ushort;
typedef unsigned long long u64;
typedef __attribute__((ext_vector_type(8))) short bf16x8;
typedef __attribute__((ext_vector_type(4))) float f32x4;

// Problem constants
#define T_STEPS 512
#define BATCH   512
#define NB      8       // batch rows per replica
#define RD      16      // inter-stage ring depth (power of 2)
#define XS      168     // xh plane row stride (ushort)
#define CSTR    12      // c-ring pad: floats per (slot,sidx) row
#define OUTC    96
#define FSTR    32      // flag stride in uints (128B line per flag)

__device__ __forceinline__ ushort f2bf(float f){
  uint u = __builtin_bit_cast(uint, f);
  u = (u + 0x7FFFu + ((u >> 16) & 1u)) >> 16;   // RNE
  return (ushort)u;
}
__device__ __forceinline__ float bf2f(ushort h){
  uint u = ((uint)h) << 16; return __builtin_bit_cast(float, u);
}
__device__ __forceinline__ float sigm(float x){
  float e = __builtin_exp2f(-1.44269504f * x);
  return __builtin_amdgcn_rcpf(1.0f + e);
}
__device__ __forceinline__ float tanh_fast(float x){
  float e = __builtin_exp2f(-2.88539008f * x);
  return 2.0f * __builtin_amdgcn_rcpf(1.0f + e) - 1.0f;
}
// Relaxed agent-scope atomics: LLC-coherent, no L1/L2 invalidate/writeback.
__device__ __forceinline__ uint aload32(const uint* p){
  return __hip_atomic_load(p, __ATOMIC_RELAXED, __HIP_MEMORY_SCOPE_AGENT);
}
__device__ __forceinline__ void astore32(uint* p, uint v){
  __hip_atomic_store(p, v, __ATOMIC_RELAXED, __HIP_MEMORY_SCOPE_AGENT);
}
__device__ __forceinline__ u64 aload64(const u64* p){
  return __hip_atomic_load(p, __ATOMIC_RELAXED, __HIP_MEMORY_SCOPE_AGENT);
}
__device__ __forceinline__ void astore64(u64* p, u64 v){
  __hip_atomic_store(p, v, __ATOMIC_RELAXED, __HIP_MEMORY_SCOPE_AGENT);
}

// 4-stage pipeline (stage = blockIdx.x>>6, rep = blockIdx.x&63), NB=8 rows.
// Steady-state wait-free protocol:
//  - data + flag loads for step t+1 issued at step t (post-B1); at step t+1's
//    preamble the PRE-LOADED flag is checked (optimistic, margin +2 steps);
//    blocking re-poll + reload only on failure (warmup/jitter).
//  - producer flag deferred: value t-1 published at B1 of step t. Preamble
//    vmcnt(1) (in-order retirement) drains store(t-2) while leaving store(t-1)
//    in flight -> store drain is off the critical path.
//  - every wave issues exactly ONE trailing hop-store instr (48 lanes/wave).
__global__ __launch_bounds__(512, 1)
void rnn_pipeline(const float* __restrict__ x,
                  const float* __restrict__ W0, const float* __restrict__ b0,
                  const float* __restrict__ W1, const float* __restrict__ b1,
                  const float* __restrict__ W2, const float* __restrict__ b2,
                  const float* __restrict__ W3, const float* __restrict__ b3,
                  const float* __restrict__ Wa, const float* __restrict__ ba,
                  float* __restrict__ y_out,
                  uint* __restrict__ prod, uint* __restrict__ consA,
                  uint* __restrict__ consB,
                  u64* __restrict__ hop0, u64* __restrict__ hop1,
                  u64* __restrict__ hop2)
{
  const int tid  = threadIdx.x;
  const int wv   = tid >> 6;      // wave 0..7
  const int lane = tid & 63;
  const int l15  = lane & 15;
  const int hi   = lane >> 4;     // 0..3
  const int rep  = blockIdx.x & 63;
  const int stage= blockIdx.x >> 6;
  const int b0r  = rep * NB;

  const int dil = (stage==0)?1:(stage==1)?3:(stage==2)?6:12;
  const int KIN = (stage==0)?64:96;
  const int K   = KIN + 64;
  const float* Wl = (stage==0)?W0:(stage==1)?W1:(stage==2)?W2:W3;
  const float* bl = (stage==0)?b0:(stage==1)?b1:(stage==2)?b2:b3;

  __shared__ __align__(16) ushort xh_hi[16*XS], xh_lo[16*XS];  // A-operand planes
  __shared__ __align__(16) float  sh_c[12*128*CSTR];           // c ring [slot][sidx][12]
  __shared__ __align__(16) ushort h_hi[12*NB*32], h_lo[12*NB*32]; // h ring planes
  __shared__ __align__(16) ushort outp[2304];  // [hi 768][lo 768] (+proj overread pad)
  __shared__ __align__(16) ushort o1p[1536];   // stage3: out1 planes
  __shared__ __align__(16) float  o3f[NB*OUTC];// stage3: out3 fp32
  __shared__ __align__(16) float  yst[512];    // stage3: deferred y (step t-1)

  for (int i = tid; i < 16*XS; i += 512){ xh_hi[i] = 0; xh_lo[i] = 0; }
  for (int i = tid; i < 12*128*CSTR; i += 512) sh_c[i] = 0.0f;
  for (int i = tid; i < 12*NB*32; i += 512){ h_hi[i] = 0; h_lo[i] = 0; }
  for (int i = tid; i < 2304; i += 512) outp[i] = 0;
  for (int i = tid; i < 1536; i += 512) o1p[i] = 0;
  for (int i = tid; i < NB*OUTC; i += 512) o3f[i] = 0.0f;

  const int sidx = 16*wv + l15;  // state index 0..127 owned by this lane

  // Layer weights as split-bf16 MFMA B-fragments (zero-padded past K).
  bf16x8 whi[4][5], wlo[4][5];
  #pragma unroll
  for (int j = 0; j < 4; ++j){
    const int grow = 128*j + sidx;
    #pragma unroll
    for (int ks = 0; ks < 5; ++ks){
      bf16x8 vh, vl;
      const int cb = ks*32 + hi*8;
      if (cb < K){
        const float* p = Wl + (size_t)grow*K + cb;
        #pragma unroll
        for (int i = 0; i < 8; ++i){
          float w = p[i];
          ushort h = f2bf(w);
          vh[i] = (short)h;
          vl[i] = (short)f2bf(w - bf2f(h));
        }
      } else {
        #pragma unroll
        for (int i = 0; i < 8; ++i){ vh[i] = 0; vl[i] = 0; }
      }
      whi[j][ks] = vh; wlo[j][ks] = vl;
    }
  }
  float bias[4];
  #pragma unroll
  for (int j = 0; j < 4; ++j) bias[j] = bl[128*j + sidx];

  // Projection weights (stage3, waves 0..3)
  bf16x8 phi[3], plo[3];
  #pragma unroll
  for (int ks = 0; ks < 3; ++ks){
    bf16x8 z;
    #pragma unroll
    for (int i = 0; i < 8; ++i) z[i]=0;
    phi[ks]=z; plo[ks]=z;
  }
  float bav = 0.0f;
  if (stage == 3 && wv < 4){
    const int ocol = 16*wv + l15;
    #pragma unroll
    for (int ks = 0; ks < 3; ++ks){
      const float* p = Wa + (size_t)ocol*96 + ks*32 + hi*8;
      bf16x8 vh, vl;
      #pragma unroll
      for (int i = 0; i < 8; ++i){
        float w = p[i];
        ushort h = f2bf(w);
        vh[i] = (short)h;
        vl[i] = (short)f2bf(w - bf2f(h));
      }
      phi[ks] = vh; plo[ks] = vl;
    }
    bav = ba[ocol];
  }

  // Flag wiring (each flag on its own 128B line)
  uint* up_prod  = (stage==1)? &prod[rep*FSTR] : (stage==2)? &prod[(64+rep)*FSTR] :
                   (stage==3)? &prod[(128+rep)*FSTR] : nullptr;
  uint* up_prod1 = (stage==3)? &prod[(64+rep)*FSTR] : nullptr;  // stage3 also needs hop1
  uint* my_prod  = (stage==0)? &prod[rep*FSTR] : (stage==1)? &prod[(64+rep)*FSTR] :
                   (stage==2)? &prod[(128+rep)*FSTR] : nullptr;
  uint* my_consA = (stage==1)? &consA[rep*FSTR] : (stage==2)? &consA[(64+rep)*FSTR] :
                   (stage==3)? &consA[(128+rep)*FSTR] : nullptr;
  uint* my_consB = (stage==3)? &consB[rep*FSTR] : nullptr;
  uint* dnA      = (stage==0)? &consA[rep*FSTR] : (stage==1)? &consA[(64+rep)*FSTR] :
                   (stage==2)? &consA[(128+rep)*FSTR] : nullptr;
  uint* dnB      = (stage==1)? &consB[rep*FSTR] : nullptr;
  const u64* hop_in  = (stage==1)? hop0 : (stage==2)? hop1 : nullptr;
  u64*       hop_out = (stage==0)? hop0 : (stage==1)? hop1 : (stage==2)? hop2 : nullptr;

  __syncthreads();

  // ---- preloop: blocking acquire of step-0 data + initial flag values ----
  u64 pfA = 0, pfB = 0; float xv = 0.0f;
  uint fvU = 0, fvU1 = 0, fvDA = 0, fvDB = 0;
  if (stage == 0){
    xv = x[(size_t)(b0r + (tid>>6))*64 + (tid&63)];
  } else if (stage < 3){
    do { fvU = aload32(up_prod); if (fvU < 3u) __builtin_amdgcn_s_sleep(2); } while (fvU < 3u);
    if (tid < 384) pfA = aload64(hop_in + (size_t)rep*384 + tid);
  } else {
    do { fvU  = aload32(up_prod);  if (fvU  < 3u) __builtin_amdgcn_s_sleep(2); } while (fvU  < 3u);
    do { fvU1 = aload32(up_prod1); if (fvU1 < 3u) __builtin_amdgcn_s_sleep(2); } while (fvU1 < 3u);
    const u64* s2 = hop2 + (size_t)rep*384;
    const u64* s1 = hop1 + (size_t)rep*384;
    pfA = (tid < 384) ? aload64(s2 + tid) : aload64(s1 + (tid - 384));
    if (tid < 256) pfB = aload64(s1 + 128 + tid);
  }

  int cur = 0, prv = dil - 1;
  for (int t = 0; t < T_STEPS; ++t){
    const int slot = t & (RD-1);

    // ---- preamble: counted drain + optimistic validity check ----
    if (stage < 3) asm volatile("s_waitcnt vmcnt(1)" ::: "memory");
    if (stage > 0){
      const bool bad = (fvU < (uint)(t+3)) || (stage==3 && fvU1 < (uint)(t+3));
      if (bad){
        if (lane == 0){
          while (aload32(up_prod) < (uint)(t+1)) __builtin_amdgcn_s_sleep(2);
          if (stage == 3)
            while (aload32(up_prod1) < (uint)(t+1)) __builtin_amdgcn_s_sleep(2);
        }
        // reconverged: flag confirmed -> reload data (race-free order)
        if (stage < 3){
          if (tid < 384) pfA = aload64(hop_in + (size_t)(slot*64 + rep)*384 + tid);
        } else {
          const u64* s2 = hop2 + (size_t)(slot*64 + rep)*384;
          const u64* s1 = hop1 + (size_t)(slot*64 + rep)*384;
          pfA = (tid < 384) ? aload64(s2 + tid) : aload64(s1 + (tid - 384));
          if (tid < 256) pfB = aload64(s1 + 128 + tid);
        }
      }
    }
    // ---- stage prefetched data to LDS ----
    if (stage == 0){
      const int r = tid >> 6, c = tid & 63;
      ushort hb = f2bf(xv);
      xh_hi[r*XS + c] = hb;
      xh_lo[r*XS + c] = f2bf(xv - bf2f(hb));
    } else {
      if (tid < 384){
        const int q = (tid < 192) ? tid : tid - 192;
        ushort* plane = (tid < 192) ? xh_hi : xh_lo;
        const int r = q / 24, c4 = (q % 24) * 4;
        *(u64*)(plane + r*XS + c4) = pfA;
      } else if (stage == 3){
        *(u64*)(o1p + 4*(tid - 384)) = pfA;
      }
      if (stage == 3 && tid < 256) *(u64*)(o1p + 4*(128 + tid)) = pfB;
    }
    // h-copy: prev_h -> cols [KIN,KIN+32), del_h -> cols [KIN+32,KIN+64)
    {
      const int which = tid >> 8, rem = tid & 255, r = rem >> 5, c = rem & 31;
      const int srcslot = (which == 1 && t >= dil) ? cur : prv;
      xh_hi[r*XS + KIN + which*32 + c] = h_hi[srcslot*(NB*32) + r*32 + c];
      xh_lo[r*XS + KIN + which*32 + c] = h_lo[srcslot*(NB*32) + r*32 + c];
    }
    __syncthreads();   // B1 (all waves drained store(t-2) via vmcnt(1))
    if (tid == 0){
      if (stage > 0){
        astore32(my_consA, (uint)(t+1));
        if (stage == 3) astore32(my_consB, (uint)(t+1));
      }
      if (stage < 3 && t >= 1) astore32(my_prod, (uint)(t-1));  // steps <= t-2 drained
    }
    // stage3: deferred y store (step t-1's projection, staged in yst)
    if (stage == 3 && t > 0){
      y_out[(size_t)((t-1)*BATCH + b0r + (tid>>6))*64 + (tid&63)] = yst[tid];
    }
    // ---- issue prefetch data + flag loads for t+1 (latency hides under GEMM+gates) ----
    const bool pre = (t + 1 < T_STEPS);
    if (pre){
      const int ns = (t + 1) & (RD-1);
      if (stage == 0){
        xv = x[(size_t)((t+1)*BATCH + b0r + (tid>>6))*64 + (tid&63)];
      } else if (stage < 3){
        if (tid < 384) pfA = aload64(hop_in + (size_t)(ns*64 + rep)*384 + tid);
        fvU = aload32(up_prod);
      } else {
        const u64* s2 = hop2 + (size_t)(ns*64 + rep)*384;
        const u64* s1 = hop1 + (size_t)(ns*64 + rep)*384;
        pfA = (tid < 384) ? aload64(s2 + tid) : aload64(s1 + (tid - 384));
        if (tid < 256) pfB = aload64(s1 + 128 + tid);
        fvU  = aload32(up_prod);
        fvU1 = aload32(up_prod1);
      }
    }
    if (stage < 3) fvDA = aload32(dnA);
    if (stage == 1) fvDB = aload32(dnB);
    asm volatile("" ::: "memory");

    // ---- GEMM: g = xh @ W^T + b  (pure ds_read + MFMA) ----
    f32x4 acc[4];
    #pragma unroll
    for (int j = 0; j < 4; ++j) acc[j] = (f32x4){bias[j],bias[j],bias[j],bias[j]};
    const int abase = l15*XS + hi*8;
    #pragma unroll
    for (int ks = 0; ks < 5; ++ks){
      if (ks*32 < K){
        bf16x8 ahi = *(const bf16x8*)(xh_hi + abase + ks*32);
        bf16x8 alo = *(const bf16x8*)(xh_lo + abase + ks*32);
        #pragma unroll
        for (int j = 0; j < 4; ++j){
          acc[j] = __builtin_amdgcn_mfma_f32_16x16x32_bf16(ahi, whi[j][ks], acc[j], 0, 0, 0);
          acc[j] = __builtin_amdgcn_mfma_f32_16x16x32_bf16(alo, whi[j][ks], acc[j], 0, 0, 0);
          acc[j] = __builtin_amdgcn_mfma_f32_16x16x32_bf16(ahi, wlo[j][ks], acc[j], 0, 0, 0);
        }
      }
    }

    // ---- gates + state update (lane owns state sidx, rows hi*4..hi*4+3) ----
    f32x4 pc = *(const f32x4*)(sh_c + prv*(128*CSTR) + sidx*CSTR + (hi&1)*4);
    f32x4 dc = *(const f32x4*)(sh_c + cur*(128*CSTR) + sidx*CSTR + (hi&1)*4);
    const bool has_prev = (t >= 1), has_del = (t >= dil);
    f32x4 ncv; float whv[4];
    #pragma unroll
    for (int k = 0; k < 4; ++k){
      float f  = sigm(acc[0][k] + 1.0f);
      float cd = tanh_fast(acc[1][k]);
      float al = sigm(acc[2][k]);
      float og = sigm(acc[3][k]);
      float wt = has_del ? (al*pc[k] + (1.0f - al)*dc[k]) : pc[k];
      float nc = has_prev ? (f*wt + (1.0f - f)*cd) : cd;
      ncv[k] = nc;
      whv[k] = og * nc;
    }
    if (hi < 2){
      *(f32x4*)(sh_c + cur*(128*CSTR) + sidx*CSTR + hi*4) = ncv;
      #pragma unroll
      for (int k = 0; k < 4; ++k){
        const int r = hi*4 + k;
        const float w = whv[k];
        if (sidx < OUTC){
          if (stage == 3){
            o3f[r*OUTC + sidx] = w;
          } else {
            ushort hb = f2bf(w);
            outp[r*OUTC + sidx]       = hb;
            outp[768 + r*OUTC + sidx] = f2bf(w - bf2f(hb));
          }
        } else {
          ushort hb = f2bf(w);
          h_hi[cur*(NB*32) + r*32 + (sidx - OUTC)] = hb;
          h_lo[cur*(NB*32) + r*32 + (sidx - OUTC)] = f2bf(w - bf2f(hb));
        }
      }
    }
    __syncthreads();   // B2

    // ---- stage output ----
    if (stage < 3){
      if (t >= RD){
        const bool badc = (fvDA < (uint)(t-13)) || (stage==1 && fvDB < (uint)(t-13));
        if (badc){
          if (lane == 0){
            while (aload32(dnA) < (uint)(t-15)) __builtin_amdgcn_s_sleep(2);
            if (stage == 1)
              while (aload32(dnB) < (uint)(t-15)) __builtin_amdgcn_s_sleep(2);
          }
        }
      }
      // single trailing store instr per wave (48 lanes each) -> clean vmcnt(1)
      if (lane < 48){
        const int g = wv*48 + lane;
        u64 v = *(const u64*)(outp + 4*g);
        astore64(hop_out + (size_t)(slot*64 + rep)*384 + g, v);   // fire & forget
      }
    } else {
      // resnet: pb = out3 + out1 -> PA planes in outp
      for (int j = tid; j < 768; j += 512){
        float v = o3f[j] + bf2f(o1p[j]) + bf2f(o1p[768 + j]);
        ushort hb = f2bf(v);
        outp[j]       = hb;
        outp[768 + j] = f2bf(v - bf2f(hb));
      }
      __syncthreads(); // B3
      if (wv < 4){
        f32x4 acc1 = (f32x4){bav, bav, bav, bav};
        const int pbase = l15*96 + hi*8;
        #pragma unroll
        for (int ks = 0; ks < 3; ++ks){
          bf16x8 ahi = *(const bf16x8*)(outp + pbase + ks*32);
          bf16x8 alo = *(const bf16x8*)(outp + 768 + pbase + ks*32);
          acc1 = __builtin_amdgcn_mfma_f32_16x16x32_bf16(ahi, phi[ks], acc1, 0, 0, 0);
          acc1 = __builtin_amdgcn_mfma_f32_16x16x32_bf16(alo, phi[ks], acc1, 0, 0, 0);
          acc1 = __builtin_amdgcn_mfma_f32_16x16x32_bf16(ahi, plo[ks], acc1, 0, 0, 0);
        }
        if (hi < 2){
          const int ocol = 16*wv + l15;
          #pragma unroll
          for (int k = 0; k < 4; ++k){
            yst[(hi*4 + k)*64 + ocol] = acc1[k];   // deferred to next step's y store
          }
        }
      }
    }
    prv = cur;
    cur = (cur + 1 == dil) ? 0 : cur + 1;
  }

  // ---- postloop: drain, final deferred y, terminal flags ----
  asm volatile("s_waitcnt vmcnt(0)" ::: "memory");
  __syncthreads();
  if (stage == 3){
    y_out[(size_t)((T_STEPS-1)*BATCH + b0r + (tid>>6))*64 + (tid&63)] = yst[tid];
  }
  if (stage < 3 && tid == 0) astore32(my_prod, (uint)(T_STEPS + 3));
}

extern "C" void kernel_launch(void* const* d_in, const int* in_sizes, int n_in,
                              void* d_out, int out_size, void* d_ws, size_t ws_size,
                              hipStream_t stream) {
  (void)in_sizes; (void)n_in; (void)out_size; (void)ws_size;
  const float* x  = (const float*)d_in[0];
  const float* W0 = (const float*)d_in[1];
  const float* b0 = (const float*)d_in[2];
  const float* W1 = (const float*)d_in[3];
  const float* b1 = (const float*)d_in[4];
  const float* W2 = (const float*)d_in[5];
  const float* b2 = (const float*)d_in[6];
  const float* W3 = (const float*)d_in[7];
  const float* b3 = (const float*)d_in[8];
  const float* Wa = (const float*)d_in[9];
  const float* ba = (const float*)d_in[10];
  float* out = (float*)d_out;

  // Flags: 128B line each. prod[3][64] @0, consA[3][64] @24576, consB[64] @49152.
  uint* prod  = (uint*)d_ws;
  uint* consA = (uint*)((char*)d_ws + 24576);
  uint* consB = (uint*)((char*)d_ws + 49152);
  u64* hop0 = (u64*)((char*)d_ws + 65536);   // [RD][64][384] u64 (hi/lo planes)
  u64* hop1 = hop0 + (size_t)RD*64*384;
  u64* hop2 = hop1 + (size_t)RD*64*384;

  hipMemsetAsync(d_ws, 0, 65536, stream);  // re-zero flags every call
  hipLaunchKernelGGL(rnn_pipeline, dim3(256), dim3(512), 0, stream,
                     x, W0, b0, W1, b1, W2, b2, W3, b3, Wa, ba,
                     out, prod, consA, consB, hop0, hop1, hop2);
}